// Round 5
// baseline (126.010 us; speedup 1.0000x reference)
//
#include <hip/hip_runtime.h>

#define NCOLORS 10
#define EPS 1e-8f
#define HW 4096
#define S_DIM 16

// One wave per half-row: row = b*16+s (8192 rows), half = 2048 floats.
// 4 waves/block, 2 rows/block, 4096 blocks. No barriers in the main loop,
// no LDS staging: pure streaming with 16 independent vector loads in flight
// per lane (fully unrolled), register histogram, butterfly reduce.
__global__ __launch_bounds__(256)
void hist_entropy(const float* __restrict__ attn,   // [B, S, HW]
                  const int* __restrict__ grids,    // [B, HW]
                  float* __restrict__ out,          // [1]
                  float inv_BS)
{
    const int tid  = threadIdx.x;
    const int lane = tid & 63;
    const int wave = tid >> 6;                    // 0..3
    const int row  = blockIdx.x * 2 + (wave >> 1);
    const int half = wave & 1;
    const int b    = row >> 4;

    const float4* a4 = (const float4*)(attn + (size_t)row * HW) + half * 512;
    const int4*   g4 = (const int4*)(grids + (size_t)b * HW) + half * 512;

    float bins[NCOLORS];
#pragma unroll
    for (int c = 0; c < NCOLORS; ++c) bins[c] = 0.f;

    // 2048 floats / 64 lanes = 8 float4 per lane; fully unrolled so all
    // 8 f4 + 8 i4 loads issue back-to-back (max MLP, no barriers).
#pragma unroll
    for (int it = 0; it < 8; ++it) {
        const float4 a = a4[it * 64 + lane];
        const int4   g = g4[it * 64 + lane];
#pragma unroll
        for (int c = 0; c < NCOLORS; ++c) {
            bins[c] += (g.x == c) ? a.x : 0.f;
            bins[c] += (g.y == c) ? a.y : 0.f;
            bins[c] += (g.z == c) ? a.z : 0.f;
            bins[c] += (g.w == c) ? a.w : 0.f;
        }
    }

    // Full 64-lane butterfly per bin (all lanes end with the wave total).
#pragma unroll
    for (int c = 0; c < NCOLORS; ++c) {
#pragma unroll
        for (int off = 32; off >= 1; off >>= 1)
            bins[c] += __shfl_xor(bins[c], off, 64);
    }

    __shared__ float wb[4][NCOLORS];
    if (lane == 0) {
#pragma unroll
        for (int c = 0; c < NCOLORS; ++c) wb[wave][c] = bins[c];
    }
    __syncthreads();

    // tid 0 -> row0 (waves 0+1), tid 128 -> row1 (waves 2+3)
    if ((tid & 127) == 0) {
        const int r2 = tid >> 7;                  // 0 or 1
        float bsum[NCOLORS];
        float tot = 0.f;
#pragma unroll
        for (int c = 0; c < NCOLORS; ++c) {
            bsum[c] = wb[r2 * 2][c] + wb[r2 * 2 + 1][c];
            tot += bsum[c];
        }
        const float inv = 1.0f / (tot + EPS);
        float e = 0.f;
#pragma unroll
        for (int c = 0; c < NCOLORS; ++c) {
            const float p = bsum[c] * inv;
            e -= p * __logf(p + EPS);
        }
        atomicAdd(out, e * inv_BS);
    }
}

extern "C" void kernel_launch(void* const* d_in, const int* in_sizes, int n_in,
                              void* d_out, int out_size, void* d_ws, size_t ws_size,
                              hipStream_t stream) {
    const float* attn  = (const float*)d_in[0];
    const int*   grids = (const int*)d_in[1];
    float*       out   = (float*)d_out;

    const int rows   = in_sizes[0] / HW;          // B*S = 8192
    const int blocks = rows / 2;                  // 4096
    const float inv_BS = 1.0f / (float)rows;

    hipMemsetAsync(out, 0, sizeof(float) * out_size, stream);
    hist_entropy<<<blocks, 256, 0, stream>>>(attn, grids, out, inv_BS);
}

// Round 6
// 29.334 us; speedup vs baseline: 4.2957x; 4.2957x over previous
//
#include <hip/hip_runtime.h>

#define NCOLORS 10
#define EPS 1e-8f
#define HW 4096
#define S_DIM 16
#define WAVES 8
#define THREADS (WAVES * 64)             // 512
#define K_PER_WAVE (HW / WAVES)          // 512
#define ITERS (K_PER_WAVE / 32)          // 16 MFMAs per wave

typedef __bf16 bf16x8 __attribute__((ext_vector_type(8)));
typedef float  f32x4  __attribute__((ext_vector_type(4)));

// Pass 1: per-b weighted color histogram via MFMA, entropy, ONE plain store
// per block to ws[b]. No atomics anywhere (R5 showed same-address atomicAdd
// serializes at ~15 ns/op and dominated at 8192 ops).
__global__ __launch_bounds__(THREADS, 4)   // VGPR <= 128 -> 2 blocks/CU
void color_entropy_pass1(const float* __restrict__ attn,   // [B, S, HW]
                         const int* __restrict__ grids,    // [B, HW]
                         float* __restrict__ ws)           // [B]
{
    const int b    = blockIdx.x;
    const int tid  = threadIdx.x;
    const int lane = tid & 63;
    const int wave = tid >> 6;      // 0..7
    const int sc   = lane & 15;     // A-row (s) AND one-hot col (color)
    const int grp  = lane >> 4;     // k sub-group within the 32-wide K tile

    const float* aBase = attn + ((size_t)b * S_DIM + sc) * HW + grp * 8;
    const int*   gBase = grids + (size_t)b * HW + grp * 8;

    const __bf16 ONE  = (__bf16)1.0f;
    const __bf16 ZER  = (__bf16)0.0f;

    f32x4 acc = {0.f, 0.f, 0.f, 0.f};

#pragma unroll 2
    for (int it = 0; it < ITERS; ++it) {
        const int k0 = wave * K_PER_WAVE + it * 32;
        const float4 f0 = *reinterpret_cast<const float4*>(aBase + k0);
        const float4 f1 = *reinterpret_cast<const float4*>(aBase + k0 + 4);
        const int4   g0 = *reinterpret_cast<const int4*>(gBase + k0);
        const int4   g1 = *reinterpret_cast<const int4*>(gBase + k0 + 4);

        bf16x8 a;
        a[0] = (__bf16)f0.x; a[1] = (__bf16)f0.y;
        a[2] = (__bf16)f0.z; a[3] = (__bf16)f0.w;
        a[4] = (__bf16)f1.x; a[5] = (__bf16)f1.y;
        a[6] = (__bf16)f1.z; a[7] = (__bf16)f1.w;

        bf16x8 oh;
        oh[0] = (g0.x == sc) ? ONE : ZER;
        oh[1] = (g0.y == sc) ? ONE : ZER;
        oh[2] = (g0.z == sc) ? ONE : ZER;
        oh[3] = (g0.w == sc) ? ONE : ZER;
        oh[4] = (g1.x == sc) ? ONE : ZER;
        oh[5] = (g1.y == sc) ? ONE : ZER;
        oh[6] = (g1.z == sc) ? ONE : ZER;
        oh[7] = (g1.w == sc) ? ONE : ZER;

        acc = __builtin_amdgcn_mfma_f32_16x16x32_bf16(a, oh, acc, 0, 0, 0);
    }

    // D layout: D[row = grp*4 + j][col = sc] = acc[j]
    __shared__ float red[WAVES][256];
#pragma unroll
    for (int j = 0; j < 4; ++j)
        red[wave][(grp * 4 + j) * 16 + sc] = acc[j];
    __syncthreads();

    if (tid < 256) {
        float s = 0.f;
#pragma unroll
        for (int w = 0; w < WAVES; ++w) s += red[w][tid];
        red[0][tid] = s;
    }
    __syncthreads();

    __shared__ float ent16[S_DIM];
    if (tid < S_DIM) {
        float bins[NCOLORS];
        float tot = 0.f;
#pragma unroll
        for (int c = 0; c < NCOLORS; ++c) {
            bins[c] = red[0][tid * 16 + c];
            tot += bins[c];
        }
        const float inv = 1.0f / (tot + EPS);
        float e = 0.f;
#pragma unroll
        for (int c = 0; c < NCOLORS; ++c) {
            const float p = bins[c] * inv;
            e -= p * __logf(p + EPS);
        }
        ent16[tid] = e;
    }
    __syncthreads();

    if (tid == 0) {
        float s = 0.f;
#pragma unroll
        for (int i = 0; i < S_DIM; ++i) s += ent16[i];
        ws[b] = s;                      // plain store — no atomic
    }
}

// Pass 2: reduce B per-block sums -> out[0]. One block, no atomics.
__global__ __launch_bounds__(512)
void color_entropy_pass2(const float* __restrict__ ws, float* __restrict__ out,
                         int n, float inv_BS)
{
    const int tid  = threadIdx.x;
    const int lane = tid & 63;
    const int wave = tid >> 6;

    float v = 0.f;
    for (int i = tid; i < n; i += 512) v += ws[i];

#pragma unroll
    for (int off = 32; off >= 1; off >>= 1)
        v += __shfl_xor(v, off, 64);

    __shared__ float s[8];
    if (lane == 0) s[wave] = v;
    __syncthreads();

    if (tid == 0) {
        float t = 0.f;
#pragma unroll
        for (int w = 0; w < 8; ++w) t += s[w];
        out[0] = t * inv_BS;
    }
}

extern "C" void kernel_launch(void* const* d_in, const int* in_sizes, int n_in,
                              void* d_out, int out_size, void* d_ws, size_t ws_size,
                              hipStream_t stream) {
    const float* attn  = (const float*)d_in[0];
    const int*   grids = (const int*)d_in[1];
    float*       out   = (float*)d_out;
    float*       ws    = (float*)d_ws;

    const int B = in_sizes[1] / HW;               // 512
    const float inv_BS = 1.0f / (float)(B * S_DIM);

    color_entropy_pass1<<<B, THREADS, 0, stream>>>(attn, grids, ws);
    color_entropy_pass2<<<1, 512, 0, stream>>>(ws, out, B, inv_BS);
}